// Round 4
// baseline (1503.922 us; speedup 1.0000x reference)
//
#include <hip/hip_runtime.h>

#define NN 50000
#define TT 24
#define HH 64
#define HORZ 12
#define EE 1600000

#define GP 256          // scatter partitions
#define EP (EE / GP)    // 6250 edges per partition (exact)
#define BK 784          // dst buckets of 64 nodes (782 used, padded)
#define NBG (BK * GP)   // 200704 cells
#define SCB (NBG / 512) // 392 scan blocks (exact)

typedef __attribute__((ext_vector_type(8))) _Float16 f16x8;
typedef __attribute__((ext_vector_type(4))) float f32x4;

__device__ __forceinline__ float sigm(float x) {
  return __builtin_amdgcn_rcpf(1.f + __expf(-x));
}
__device__ __forceinline__ float tanh_f(float x) {
  return 1.f - 2.f * __builtin_amdgcn_rcpf(1.f + __expf(2.f * x));
}

// ---------- build all fp16 MFMA B-fragments in one launch ----------
// frag layout per weight: [nf][kf(2)][lane(64)][8]; B[k][col]=W[col][k],
// col=16*nf+(l&15), k=32*kf+8*(l>>4)+j. Regions: whh 12288 | gc1 4096 | gc2 4096 | fc 1024.
__global__ void build_frags_kernel(const float* __restrict__ whh, const float* __restrict__ g1,
                                   const float* __restrict__ g2, const float* __restrict__ fcw,
                                   _Float16* __restrict__ frag) {
  int idx = blockIdx.x * 256 + threadIdx.x;
  if (idx >= 21504) return;
  const float* W;
  int rows, li;
  if (idx < 12288) { W = whh; rows = 192; li = idx; }
  else if (idx < 16384) { W = g1; rows = 64; li = idx - 12288; }
  else if (idx < 20480) { W = g2; rows = 64; li = idx - 16384; }
  else { W = fcw; rows = HORZ; li = idx - 20480; }
  int j = li & 7;
  int l = (li >> 3) & 63;
  int kf = (li >> 9) & 1;
  int nf = li >> 10;
  int col = 16 * nf + (l & 15);
  int k = 32 * kf + 8 * (l >> 4) + j;
  frag[idx] = (col < rows) ? (_Float16)W[col * 64 + k] : (_Float16)0.f;
}

// ---------- MFMA GRU, gate-quarter split, double-buffered h (1 barrier/step) ----------
__global__ __launch_bounds__(256, 6) void gru_kernel(
    const float* __restrict__ x, const float* __restrict__ w_ih,
    const float* __restrict__ b_ih, const float* __restrict__ b_hh,
    const _Float16* __restrict__ wfrag, _Float16* __restrict__ hout) {
  __shared__ __align__(16) _Float16 sh[2][16][72];  // [buf][node][dim], 144B rows

  const int tid = threadIdx.x;
  const int lane = tid & 63;
  const int w = tid >> 6;   // gate quarter 0..3
  const int c = lane & 15;
  const int q = lane >> 4;
  const int d = 16 * w + c;  // owned gate dim

  f16x8 Br0 = *(const f16x8*)&wfrag[(((w)*2 + 0) * 64 + lane) * 8];
  f16x8 Br1 = *(const f16x8*)&wfrag[(((w)*2 + 1) * 64 + lane) * 8];
  f16x8 Bz0 = *(const f16x8*)&wfrag[(((4 + w) * 2 + 0) * 64 + lane) * 8];
  f16x8 Bz1 = *(const f16x8*)&wfrag[(((4 + w) * 2 + 1) * 64 + lane) * 8];
  f16x8 Bn0 = *(const f16x8*)&wfrag[(((8 + w) * 2 + 0) * 64 + lane) * 8];
  f16x8 Bn1 = *(const f16x8*)&wfrag[(((8 + w) * 2 + 1) * 64 + lane) * 8];

  const float wir = w_ih[d], wiz = w_ih[64 + d], win = w_ih[128 + d];
  const float arb = b_ih[d] + b_hh[d];
  const float azb = b_ih[64 + d] + b_hh[64 + d];
  const float bin = b_ih[128 + d];
  const float bhn = b_hh[128 + d];

  const int base = blockIdx.x * 16;  // 3125 blocks exact
  const float* xb = x + base * TT;

  float hreg[4] = {0.f, 0.f, 0.f, 0.f};

#pragma unroll 1
  for (int t = 0; t < TT; ++t) {
    f32x4 ar = (f32x4){arb, arb, arb, arb};
    f32x4 az = (f32x4){azb, azb, azb, azb};
    f32x4 an = (f32x4){bhn, bhn, bhn, bhn};
    if (t > 0) {
      const _Float16* S = &sh[(t & 1) ^ 1][0][0];
      f16x8 a0 = *(const f16x8*)&S[c * 72 + 8 * q];
      f16x8 a1 = *(const f16x8*)&S[c * 72 + 32 + 8 * q];
      ar = __builtin_amdgcn_mfma_f32_16x16x32_f16(a0, Br0, ar, 0, 0, 0);
      az = __builtin_amdgcn_mfma_f32_16x16x32_f16(a0, Bz0, az, 0, 0, 0);
      an = __builtin_amdgcn_mfma_f32_16x16x32_f16(a0, Bn0, an, 0, 0, 0);
      ar = __builtin_amdgcn_mfma_f32_16x16x32_f16(a1, Br1, ar, 0, 0, 0);
      az = __builtin_amdgcn_mfma_f32_16x16x32_f16(a1, Bz1, az, 0, 0, 0);
      an = __builtin_amdgcn_mfma_f32_16x16x32_f16(a1, Bn1, an, 0, 0, 0);
    }
#pragma unroll
    for (int r = 0; r < 4; ++r) {
      float xt = xb[(4 * q + r) * TT + t];
      float rg = sigm(xt * wir + ar[r]);
      float zg = sigm(xt * wiz + az[r]);
      float nn = tanh_f(rg * an[r] + (xt * win + bin));
      float hn = nn + zg * (hreg[r] - nn);
      hreg[r] = hn;
      sh[t & 1][4 * q + r][d] = (_Float16)hn;
    }
    __syncthreads();  // step-t writes visible before step-t+1 reads
  }

#pragma unroll
  for (int r = 0; r < 4; ++r) hout[(base + 4 * q + r) * 64 + d] = (_Float16)hreg[r];
}

// ---------- P1: per-partition bucket histogram ----------
__global__ __launch_bounds__(256) void p1_hist_kernel(const int* __restrict__ dst,
                                                      int* __restrict__ hist) {
  __shared__ int h[BK];
  int tid = threadIdx.x, g = blockIdx.x;
  for (int b = tid; b < BK; b += 256) h[b] = 0;
  __syncthreads();
  int e0 = g * EP;
  for (int i = tid; i < EP; i += 256) atomicAdd(&h[dst[e0 + i] >> 6], 1);
  __syncthreads();
  for (int b = tid; b < BK; b += 256) hist[b * GP + g] = h[b];
}

// ---------- scan over NBG cells (exact 392x512) ----------
__global__ void scanA_kernel(const int* __restrict__ v, int* __restrict__ part) {
  __shared__ int s[512];
  int i = blockIdx.x * 512 + threadIdx.x;
  s[threadIdx.x] = v[i];
  __syncthreads();
  for (int off = 256; off > 0; off >>= 1) {
    if (threadIdx.x < off) s[threadIdx.x] += s[threadIdx.x + off];
    __syncthreads();
  }
  if (threadIdx.x == 0) part[blockIdx.x] = s[0];
}

__global__ void scanB_kernel(int* __restrict__ part) {
  __shared__ int s[512];
  int t = threadIdx.x;
  int v = (t < SCB) ? part[t] : 0;
  s[t] = v;
  __syncthreads();
  for (int off = 1; off < 512; off <<= 1) {
    int a = s[t];
    int b = (t >= off) ? s[t - off] : 0;
    __syncthreads();
    s[t] = a + b;
    __syncthreads();
  }
  if (t < SCB) part[t] = s[t] - v;  // exclusive
}

// in-place: cellbase[i] = exclusive_prefix(hist)[i]
__global__ void scanC_kernel(int* __restrict__ cellbase, const int* __restrict__ part) {
  __shared__ int s[2][512];
  int tid = threadIdx.x;
  int i = blockIdx.x * 512 + tid;
  int x = cellbase[i];
  s[0][tid] = x;
  __syncthreads();
  int cur = 0;
  for (int off = 1; off < 512; off <<= 1) {
    int nxt = cur ^ 1;
    int val = s[cur][tid] + ((tid >= off) ? s[cur][tid - off] : 0);
    s[nxt][tid] = val;
    __syncthreads();
    cur = nxt;
  }
  cellbase[i] = part[blockIdx.x] + s[cur][tid] - x;
  if (i == 0) cellbase[NBG] = EE;
}

// ---------- P2: bucketed scatter of packed records, LDS cursors, no global atomics ----------
__global__ __launch_bounds__(256) void p2_scatter_kernel(
    const int* __restrict__ src, const int* __restrict__ dst,
    const int* __restrict__ cellbase, unsigned int* __restrict__ rec) {
  __shared__ int cur[BK];
  int tid = threadIdx.x, g = blockIdx.x;
  for (int b = tid; b < BK; b += 256) cur[b] = cellbase[b * GP + g];
  __syncthreads();
  int e0 = g * EP;
  for (int i = tid; i < EP; i += 256) {
    int e = e0 + i;
    int d = dst[e];
    int s = src[e];
    int p = atomicAdd(&cur[d >> 6], 1);
    rec[p] = ((unsigned)(d & 63) << 16) | (unsigned)s;
  }
}

// ---------- per-bucket degree -> dinv ----------
__global__ __launch_bounds__(256) void deg_kernel(const unsigned int* __restrict__ rec,
                                                  const int* __restrict__ cellbase,
                                                  float* __restrict__ dinv) {
  __shared__ int cnt[64];
  int b = blockIdx.x, tid = threadIdx.x;
  if (tid < 64) cnt[tid] = 0;
  __syncthreads();
  int e0 = cellbase[b * GP], e1 = cellbase[(b + 1) * GP];
  for (int e = e0 + tid; e < e1; e += 256) atomicAdd(&cnt[rec[e] >> 16], 1);
  __syncthreads();
  if (tid < 64) {
    int n = b * 64 + tid;
    if (n < NN) dinv[n] = rsqrtf((float)(cnt[tid] + 1));  // +1 self loop
  }
}

// ---------- MFMA linear: out[n] = f16( dinv[n] * (h[n] @ W^T) ) ----------
__global__ __launch_bounds__(256) void linear_mfma_kernel(
    const _Float16* __restrict__ hin, const _Float16* __restrict__ frag,
    const float* __restrict__ dinv, _Float16* __restrict__ out) {
  const int tid = threadIdx.x;
  const int lane = tid & 63;
  const int w = tid >> 6;
  const int c = lane & 15;
  const int q = lane >> 4;
  int n0 = blockIdx.x * 64 + w * 16;
  int nA = n0 + c;
  int nc = nA < NN ? nA : NN - 1;
  const _Float16* hp = hin + nc * 64;

  f16x8 a0 = *(const f16x8*)&hp[8 * q];
  f16x8 a1 = *(const f16x8*)&hp[32 + 8 * q];
  f32x4 acc[4];
#pragma unroll
  for (int nf = 0; nf < 4; ++nf) acc[nf] = (f32x4){0.f, 0.f, 0.f, 0.f};
#pragma unroll
  for (int nf = 0; nf < 4; ++nf) {
    f16x8 b0 = *(const f16x8*)&frag[((nf * 2 + 0) * 64 + lane) * 8];
    acc[nf] = __builtin_amdgcn_mfma_f32_16x16x32_f16(a0, b0, acc[nf], 0, 0, 0);
  }
#pragma unroll
  for (int nf = 0; nf < 4; ++nf) {
    f16x8 b1 = *(const f16x8*)&frag[((nf * 2 + 1) * 64 + lane) * 8];
    acc[nf] = __builtin_amdgcn_mfma_f32_16x16x32_f16(a1, b1, acc[nf], 0, 0, 0);
  }
#pragma unroll
  for (int r = 0; r < 4; ++r) {
    int n = n0 + 4 * q + r;
    if (n < NN) {
      float dn = dinv[n];
#pragma unroll
      for (int nf = 0; nf < 4; ++nf)
        out[n * 64 + c + 16 * nf] = (_Float16)(acc[nf][r] * dn);
    }
  }
}

// ---------- bucketed aggregation: block = 64-node bucket, fp32 LDS accumulators ----------
__global__ __launch_bounds__(256) void agg_kernel(
    const _Float16* __restrict__ hwp, const float* __restrict__ dinv,
    const unsigned int* __restrict__ rec, const int* __restrict__ cellbase,
    const float* __restrict__ bias, _Float16* __restrict__ out) {
  __shared__ float sacc[64 * 64];  // 16 KB
  int tid = threadIdx.x, b = blockIdx.x;
  int nb = b * 64;
  for (int idx = tid; idx < 4096; idx += 256) {
    int row = idx >> 6, col = idx & 63;
    int n = nb + row;
    sacc[idx] = (n < NN) ? (float)hwp[n * 64 + col] : 0.f;  // self loop, dinv-scaled
  }
  __syncthreads();
  int e0 = cellbase[b * GP], e1 = cellbase[(b + 1) * GP];
  int lane = tid & 63, w = tid >> 6;
  for (int e = e0 + w * 4; e < e1; e += 16) {
    unsigned int r[4];
    float v[4];
#pragma unroll
    for (int k = 0; k < 4; ++k) {
      int ee = e + k;
      r[k] = (ee < e1) ? rec[ee] : 0u;
    }
#pragma unroll
    for (int k = 0; k < 4; ++k)
      v[k] = (e + k < e1) ? (float)hwp[(r[k] & 0xFFFFu) * 64 + lane] : 0.f;
#pragma unroll
    for (int k = 0; k < 4; ++k)
      atomicAdd(&sacc[(r[k] >> 16) * 64 + lane], v[k]);
  }
  __syncthreads();
  for (int idx = tid; idx < 4096; idx += 256) {
    int row = idx >> 6, col = idx & 63;
    int n = nb + row;
    if (n < NN) {
      float v = sacc[idx] * dinv[n] + bias[col];
      out[n * 64 + col] = (_Float16)(v > 0.f ? v : 0.f);
    }
  }
}

// ---------- MFMA final FC (64 -> 12, padded to 16) ----------
__global__ __launch_bounds__(256) void fc_mfma_kernel(
    const _Float16* __restrict__ hin, const _Float16* __restrict__ frag,
    const float* __restrict__ bias, float* __restrict__ out) {
  const int tid = threadIdx.x;
  const int lane = tid & 63;
  const int w = tid >> 6;
  const int c = lane & 15;
  const int q = lane >> 4;
  int n0 = blockIdx.x * 64 + w * 16;
  int nA = n0 + c;
  int nc = nA < NN ? nA : NN - 1;
  const _Float16* hp = hin + nc * 64;

  f16x8 a0 = *(const f16x8*)&hp[8 * q];
  f16x8 a1 = *(const f16x8*)&hp[32 + 8 * q];
  float bc = (c < HORZ) ? bias[c] : 0.f;
  f32x4 acc = (f32x4){bc, bc, bc, bc};
  f16x8 b0 = *(const f16x8*)&frag[(0 * 64 + lane) * 8];
  f16x8 b1 = *(const f16x8*)&frag[(1 * 64 + lane) * 8];
  acc = __builtin_amdgcn_mfma_f32_16x16x32_f16(a0, b0, acc, 0, 0, 0);
  acc = __builtin_amdgcn_mfma_f32_16x16x32_f16(a1, b1, acc, 0, 0, 0);
  if (c < HORZ) {
#pragma unroll
    for (int r = 0; r < 4; ++r) {
      int n = n0 + 4 * q + r;
      if (n < NN) out[n * HORZ + c] = acc[r];
    }
  }
}

extern "C" void kernel_launch(void* const* d_in, const int* in_sizes, int n_in,
                              void* d_out, int out_size, void* d_ws, size_t ws_size,
                              hipStream_t stream) {
  (void)in_sizes; (void)n_in; (void)out_size; (void)ws_size;
  const float* x = (const float*)d_in[0];
  const int* edge_index = (const int*)d_in[1];
  const float* w_ih = (const float*)d_in[2];
  const float* w_hh = (const float*)d_in[3];
  const float* b_ih = (const float*)d_in[4];
  const float* b_hh = (const float*)d_in[5];
  const float* gc1_w = (const float*)d_in[6];
  const float* gc1_b = (const float*)d_in[7];
  const float* gc2_w = (const float*)d_in[8];
  const float* gc2_b = (const float*)d_in[9];
  const float* fc_w = (const float*)d_in[10];
  const float* fc_b = (const float*)d_in[11];
  float* out = (float*)d_out;

  // workspace layout
  char* ws = (char*)d_ws;
  _Float16* wfrag = (_Float16*)ws;           // 12288
  _Float16* l1f = wfrag + 12288;             // 4096
  _Float16* l2f = l1f + 4096;                // 4096
  _Float16* fcf = l2f + 4096;                // 1024  -> 21504 halves = 43008 B
  _Float16* hbuf = (_Float16*)(ws + 43008);  // NN*64 f16
  _Float16* hw = hbuf + NN * 64;             // NN*64 f16
  float* dinv = (float*)(hw + NN * 64);      // NN f32
  int* cellbase = (int*)(dinv + NN);         // NBG+1 (hist, scanned in place)
  unsigned int* recs = (unsigned int*)(cellbase + NBG + 1);  // EE
  int* part = (int*)(recs + EE);             // SCB

  const int* esrc = edge_index;
  const int* edst = edge_index + EE;

  build_frags_kernel<<<84, 256, 0, stream>>>(w_hh, gc1_w, gc2_w, fc_w, wfrag);
  gru_kernel<<<NN / 16, 256, 0, stream>>>(x, w_ih, b_ih, b_hh, wfrag, hbuf);

  p1_hist_kernel<<<GP, 256, 0, stream>>>(edst, cellbase);
  scanA_kernel<<<SCB, 512, 0, stream>>>(cellbase, part);
  scanB_kernel<<<1, 512, 0, stream>>>(part);
  scanC_kernel<<<SCB, 512, 0, stream>>>(cellbase, part);
  p2_scatter_kernel<<<GP, 256, 0, stream>>>(esrc, edst, cellbase, recs);
  deg_kernel<<<BK, 256, 0, stream>>>(recs, cellbase, dinv);

  linear_mfma_kernel<<<(NN + 63) / 64, 256, 0, stream>>>(hbuf, l1f, dinv, hw);
  agg_kernel<<<BK, 256, 0, stream>>>(hw, dinv, recs, cellbase, gc1_b, hbuf);
  linear_mfma_kernel<<<(NN + 63) / 64, 256, 0, stream>>>(hbuf, l2f, dinv, hw);
  agg_kernel<<<BK, 256, 0, stream>>>(hw, dinv, recs, cellbase, gc2_b, hbuf);
  fc_mfma_kernel<<<(NN + 63) / 64, 256, 0, stream>>>(hbuf, fcf, fc_b, out);
}

// Round 5
// 259.663 us; speedup vs baseline: 5.7918x; 5.7918x over previous
//
#include <hip/hip_runtime.h>

#define NN 50000
#define TT 24
#define HH 64
#define HORZ 12
#define EE 1600000

#define GP 256          // scatter partitions
#define EP (EE / GP)    // 6250 edges per partition (exact)
#define BK 784          // dst buckets of 64 nodes (782 used, padded)
#define NBG (BK * GP)   // 200704 cells
#define SCB (NBG / 512) // 392 scan blocks (exact)

typedef __attribute__((ext_vector_type(8))) _Float16 f16x8;
typedef __attribute__((ext_vector_type(4))) float f32x4;

__device__ __forceinline__ float sigm(float x) {
  return __builtin_amdgcn_rcpf(1.f + __expf(-x));
}
__device__ __forceinline__ float tanh_f(float x) {
  return 1.f - 2.f * __builtin_amdgcn_rcpf(1.f + __expf(2.f * x));
}

// ---------- build all fp16 MFMA B-fragments in one launch ----------
// frag layout per weight: [nf][kf(2)][lane(64)][8]; B[k][col]=W[col][k],
// col=16*nf+(l&15), k=32*kf+8*(l>>4)+j. Regions: whh 12288 | gc1 4096 | gc2 4096 | fc 1024.
__global__ void build_frags_kernel(const float* __restrict__ whh, const float* __restrict__ g1,
                                   const float* __restrict__ g2, const float* __restrict__ fcw,
                                   _Float16* __restrict__ frag) {
  int idx = blockIdx.x * 256 + threadIdx.x;
  if (idx >= 21504) return;
  const float* W;
  int rows, li;
  if (idx < 12288) { W = whh; rows = 192; li = idx; }
  else if (idx < 16384) { W = g1; rows = 64; li = idx - 12288; }
  else if (idx < 20480) { W = g2; rows = 64; li = idx - 16384; }
  else { W = fcw; rows = HORZ; li = idx - 20480; }
  int j = li & 7;
  int l = (li >> 3) & 63;
  int kf = (li >> 9) & 1;
  int nf = li >> 10;
  int col = 16 * nf + (l & 15);
  int k = 32 * kf + 8 * (l >> 4) + j;
  frag[idx] = (col < rows) ? (_Float16)W[col * 64 + k] : (_Float16)0.f;
}

// ---------- MFMA GRU, gate-quarter split, double-buffered h (1 barrier/step) ----------
__global__ __launch_bounds__(256, 6) void gru_kernel(
    const float* __restrict__ x, const float* __restrict__ w_ih,
    const float* __restrict__ b_ih, const float* __restrict__ b_hh,
    const _Float16* __restrict__ wfrag, _Float16* __restrict__ hout) {
  __shared__ __align__(16) _Float16 sh[2][16][72];  // [buf][node][dim], 144B rows

  const int tid = threadIdx.x;
  const int lane = tid & 63;
  const int w = tid >> 6;   // gate quarter 0..3
  const int c = lane & 15;
  const int q = lane >> 4;
  const int d = 16 * w + c;  // owned gate dim

  f16x8 Br0 = *(const f16x8*)&wfrag[(((w)*2 + 0) * 64 + lane) * 8];
  f16x8 Br1 = *(const f16x8*)&wfrag[(((w)*2 + 1) * 64 + lane) * 8];
  f16x8 Bz0 = *(const f16x8*)&wfrag[(((4 + w) * 2 + 0) * 64 + lane) * 8];
  f16x8 Bz1 = *(const f16x8*)&wfrag[(((4 + w) * 2 + 1) * 64 + lane) * 8];
  f16x8 Bn0 = *(const f16x8*)&wfrag[(((8 + w) * 2 + 0) * 64 + lane) * 8];
  f16x8 Bn1 = *(const f16x8*)&wfrag[(((8 + w) * 2 + 1) * 64 + lane) * 8];

  const float wir = w_ih[d], wiz = w_ih[64 + d], win = w_ih[128 + d];
  const float arb = b_ih[d] + b_hh[d];
  const float azb = b_ih[64 + d] + b_hh[64 + d];
  const float bin = b_ih[128 + d];
  const float bhn = b_hh[128 + d];

  const int base = blockIdx.x * 16;  // 3125 blocks exact
  const float* xb = x + base * TT;

  float hreg[4] = {0.f, 0.f, 0.f, 0.f};

#pragma unroll 1
  for (int t = 0; t < TT; ++t) {
    f32x4 ar = (f32x4){arb, arb, arb, arb};
    f32x4 az = (f32x4){azb, azb, azb, azb};
    f32x4 an = (f32x4){bhn, bhn, bhn, bhn};
    if (t > 0) {
      const _Float16* S = &sh[(t & 1) ^ 1][0][0];
      f16x8 a0 = *(const f16x8*)&S[c * 72 + 8 * q];
      f16x8 a1 = *(const f16x8*)&S[c * 72 + 32 + 8 * q];
      ar = __builtin_amdgcn_mfma_f32_16x16x32_f16(a0, Br0, ar, 0, 0, 0);
      az = __builtin_amdgcn_mfma_f32_16x16x32_f16(a0, Bz0, az, 0, 0, 0);
      an = __builtin_amdgcn_mfma_f32_16x16x32_f16(a0, Bn0, an, 0, 0, 0);
      ar = __builtin_amdgcn_mfma_f32_16x16x32_f16(a1, Br1, ar, 0, 0, 0);
      az = __builtin_amdgcn_mfma_f32_16x16x32_f16(a1, Bz1, az, 0, 0, 0);
      an = __builtin_amdgcn_mfma_f32_16x16x32_f16(a1, Bn1, an, 0, 0, 0);
    }
#pragma unroll
    for (int r = 0; r < 4; ++r) {
      float xt = xb[(4 * q + r) * TT + t];
      float rg = sigm(xt * wir + ar[r]);
      float zg = sigm(xt * wiz + az[r]);
      float nn = tanh_f(rg * an[r] + (xt * win + bin));
      float hn = nn + zg * (hreg[r] - nn);
      hreg[r] = hn;
      sh[t & 1][4 * q + r][d] = (_Float16)hn;
    }
    __syncthreads();  // step-t writes visible before step-t+1 reads
  }

#pragma unroll
  for (int r = 0; r < 4; ++r) hout[(base + 4 * q + r) * 64 + d] = (_Float16)hreg[r];
}

// ---------- P1: per-partition bucket histogram ----------
__global__ __launch_bounds__(256) void p1_hist_kernel(const int* __restrict__ dst,
                                                      int* __restrict__ hist) {
  __shared__ int h[BK];
  int tid = threadIdx.x, g = blockIdx.x;
  for (int b = tid; b < BK; b += 256) h[b] = 0;
  __syncthreads();
  int e0 = g * EP;
  for (int i = tid; i < EP; i += 256) atomicAdd(&h[dst[e0 + i] >> 6], 1);
  __syncthreads();
  for (int b = tid; b < BK; b += 256) hist[b * GP + g] = h[b];
}

// ---------- scan over NBG cells (exact 392x512) ----------
__global__ void scanA_kernel(const int* __restrict__ v, int* __restrict__ part) {
  __shared__ int s[512];
  int i = blockIdx.x * 512 + threadIdx.x;
  s[threadIdx.x] = v[i];
  __syncthreads();
  for (int off = 256; off > 0; off >>= 1) {
    if (threadIdx.x < off) s[threadIdx.x] += s[threadIdx.x + off];
    __syncthreads();
  }
  if (threadIdx.x == 0) part[blockIdx.x] = s[0];
}

__global__ void scanB_kernel(int* __restrict__ part) {
  __shared__ int s[512];
  int t = threadIdx.x;
  int v = (t < SCB) ? part[t] : 0;
  s[t] = v;
  __syncthreads();
  for (int off = 1; off < 512; off <<= 1) {
    int a = s[t];
    int b = (t >= off) ? s[t - off] : 0;
    __syncthreads();
    s[t] = a + b;
    __syncthreads();
  }
  if (t < SCB) part[t] = s[t] - v;  // exclusive
}

// in-place: cellbase[i] = exclusive_prefix(hist)[i]
__global__ void scanC_kernel(int* __restrict__ cellbase, const int* __restrict__ part) {
  __shared__ int s[2][512];
  int tid = threadIdx.x;
  int i = blockIdx.x * 512 + tid;
  int x = cellbase[i];
  s[0][tid] = x;
  __syncthreads();
  int cur = 0;
  for (int off = 1; off < 512; off <<= 1) {
    int nxt = cur ^ 1;
    int val = s[cur][tid] + ((tid >= off) ? s[cur][tid - off] : 0);
    s[nxt][tid] = val;
    __syncthreads();
    cur = nxt;
  }
  cellbase[i] = part[blockIdx.x] + s[cur][tid] - x;
  if (i == 0) cellbase[NBG] = EE;
}

// ---------- P2: bucketed scatter of packed records, LDS cursors, no global atomics ----------
__global__ __launch_bounds__(256) void p2_scatter_kernel(
    const int* __restrict__ src, const int* __restrict__ dst,
    const int* __restrict__ cellbase, unsigned int* __restrict__ rec) {
  __shared__ int cur[BK];
  int tid = threadIdx.x, g = blockIdx.x;
  for (int b = tid; b < BK; b += 256) cur[b] = cellbase[b * GP + g];
  __syncthreads();
  int e0 = g * EP;
  for (int i = tid; i < EP; i += 256) {
    int e = e0 + i;
    int d = dst[e];
    int s = src[e];
    int p = atomicAdd(&cur[d >> 6], 1);
    rec[p] = ((unsigned)(d & 63) << 16) | (unsigned)s;
  }
}

// ---------- second-level sort: bucket records -> node-ordered ushort CSR + row_start + dinv ----------
__global__ __launch_bounds__(256) void sort2_kernel(
    const unsigned int* __restrict__ rec, const int* __restrict__ cellbase,
    unsigned short* __restrict__ csr, int* __restrict__ row_start,
    float* __restrict__ dinv) {
  __shared__ int cnt[64];
  __shared__ int cur[64];
  int b = blockIdx.x, tid = threadIdx.x;
  if (tid < 64) cnt[tid] = 0;
  __syncthreads();
  int e0 = cellbase[b * GP], e1 = cellbase[(b + 1) * GP];
  for (int e = e0 + tid; e < e1; e += 256) atomicAdd(&cnt[rec[e] >> 16], 1);
  __syncthreads();
  if (tid == 0) {
    int a = e0;
#pragma unroll
    for (int l = 0; l < 64; ++l) { int c = cnt[l]; cur[l] = a; a += c; }
  }
  __syncthreads();
  if (tid < 64) {
    int n = b * 64 + tid;
    if (n <= NN) row_start[n] = cur[tid];
    if (n < NN) dinv[n] = rsqrtf((float)(cnt[tid] + 1));  // +1 self loop
  }
  __syncthreads();  // row_start reads of cur complete before atomic mutation
  for (int e = e0 + tid; e < e1; e += 256) {
    unsigned int r = rec[e];
    int p = atomicAdd(&cur[r >> 16], 1);
    csr[p] = (unsigned short)(r & 0xFFFFu);
  }
}

// ---------- MFMA linear: out[n] = f16( dinv[n] * (h[n] @ W^T) ) ----------
__global__ __launch_bounds__(256) void linear_mfma_kernel(
    const _Float16* __restrict__ hin, const _Float16* __restrict__ frag,
    const float* __restrict__ dinv, _Float16* __restrict__ out) {
  const int tid = threadIdx.x;
  const int lane = tid & 63;
  const int w = tid >> 6;
  const int c = lane & 15;
  const int q = lane >> 4;
  int n0 = blockIdx.x * 64 + w * 16;
  int nA = n0 + c;
  int nc = nA < NN ? nA : NN - 1;
  const _Float16* hp = hin + nc * 64;

  f16x8 a0 = *(const f16x8*)&hp[8 * q];
  f16x8 a1 = *(const f16x8*)&hp[32 + 8 * q];
  f32x4 acc[4];
#pragma unroll
  for (int nf = 0; nf < 4; ++nf) acc[nf] = (f32x4){0.f, 0.f, 0.f, 0.f};
#pragma unroll
  for (int nf = 0; nf < 4; ++nf) {
    f16x8 b0 = *(const f16x8*)&frag[((nf * 2 + 0) * 64 + lane) * 8];
    acc[nf] = __builtin_amdgcn_mfma_f32_16x16x32_f16(a0, b0, acc[nf], 0, 0, 0);
  }
#pragma unroll
  for (int nf = 0; nf < 4; ++nf) {
    f16x8 b1 = *(const f16x8*)&frag[((nf * 2 + 1) * 64 + lane) * 8];
    acc[nf] = __builtin_amdgcn_mfma_f32_16x16x32_f16(a1, b1, acc[nf], 0, 0, 0);
  }
#pragma unroll
  for (int r = 0; r < 4; ++r) {
    int n = n0 + 4 * q + r;
    if (n < NN) {
      float dn = dinv[n];
#pragma unroll
      for (int nf = 0; nf < 4; ++nf)
        out[n * 64 + c + 16 * nf] = (_Float16)(acc[nf][r] * dn);
    }
  }
}

// ---------- CSR aggregation, wave per node, uint4-packed ushort indices ----------
__global__ __launch_bounds__(256) void agg_kernel(
    const _Float16* __restrict__ hwp, const float* __restrict__ dinv,
    const int* __restrict__ row_start, const unsigned short* __restrict__ csr,
    const float* __restrict__ bias, _Float16* __restrict__ out) {
  int wid = blockIdx.x * 4 + (threadIdx.x >> 6);
  int lane = threadIdx.x & 63;
  if (wid >= NN) return;
  int e0 = row_start[wid], e1 = row_start[wid + 1];
  float a0 = (float)hwp[wid * 64 + lane];  // self loop (already dinv-scaled)
  float a1 = 0.f, a2 = 0.f, a3 = 0.f;
  int e = e0;
  for (; e < e1 && (e & 7); ++e) a0 += (float)hwp[(int)csr[e] * 64 + lane];
  for (; e + 8 <= e1; e += 8) {
    uint4 pk = *(const uint4*)&csr[e];  // 8 indices, one 16B load
    int s0 = pk.x & 0xFFFF, s1 = pk.x >> 16;
    int s2 = pk.y & 0xFFFF, s3 = pk.y >> 16;
    int s4 = pk.z & 0xFFFF, s5 = pk.z >> 16;
    int s6 = pk.w & 0xFFFF, s7 = pk.w >> 16;
    a0 += (float)hwp[s0 * 64 + lane];
    a1 += (float)hwp[s1 * 64 + lane];
    a2 += (float)hwp[s2 * 64 + lane];
    a3 += (float)hwp[s3 * 64 + lane];
    a0 += (float)hwp[s4 * 64 + lane];
    a1 += (float)hwp[s5 * 64 + lane];
    a2 += (float)hwp[s6 * 64 + lane];
    a3 += (float)hwp[s7 * 64 + lane];
  }
  for (; e < e1; ++e) a0 += (float)hwp[(int)csr[e] * 64 + lane];
  float v = (a0 + a1 + a2 + a3) * dinv[wid] + bias[lane];
  out[wid * 64 + lane] = (_Float16)(v > 0.f ? v : 0.f);
}

// ---------- MFMA final FC (64 -> 12, padded to 16) ----------
__global__ __launch_bounds__(256) void fc_mfma_kernel(
    const _Float16* __restrict__ hin, const _Float16* __restrict__ frag,
    const float* __restrict__ bias, float* __restrict__ out) {
  const int tid = threadIdx.x;
  const int lane = tid & 63;
  const int w = tid >> 6;
  const int c = lane & 15;
  const int q = lane >> 4;
  int n0 = blockIdx.x * 64 + w * 16;
  int nA = n0 + c;
  int nc = nA < NN ? nA : NN - 1;
  const _Float16* hp = hin + nc * 64;

  f16x8 a0 = *(const f16x8*)&hp[8 * q];
  f16x8 a1 = *(const f16x8*)&hp[32 + 8 * q];
  float bc = (c < HORZ) ? bias[c] : 0.f;
  f32x4 acc = (f32x4){bc, bc, bc, bc};
  f16x8 b0 = *(const f16x8*)&frag[(0 * 64 + lane) * 8];
  f16x8 b1 = *(const f16x8*)&frag[(1 * 64 + lane) * 8];
  acc = __builtin_amdgcn_mfma_f32_16x16x32_f16(a0, b0, acc, 0, 0, 0);
  acc = __builtin_amdgcn_mfma_f32_16x16x32_f16(a1, b1, acc, 0, 0, 0);
  if (c < HORZ) {
#pragma unroll
    for (int r = 0; r < 4; ++r) {
      int n = n0 + 4 * q + r;
      if (n < NN) out[n * HORZ + c] = acc[r];
    }
  }
}

extern "C" void kernel_launch(void* const* d_in, const int* in_sizes, int n_in,
                              void* d_out, int out_size, void* d_ws, size_t ws_size,
                              hipStream_t stream) {
  (void)in_sizes; (void)n_in; (void)out_size; (void)ws_size;
  const float* x = (const float*)d_in[0];
  const int* edge_index = (const int*)d_in[1];
  const float* w_ih = (const float*)d_in[2];
  const float* w_hh = (const float*)d_in[3];
  const float* b_ih = (const float*)d_in[4];
  const float* b_hh = (const float*)d_in[5];
  const float* gc1_w = (const float*)d_in[6];
  const float* gc1_b = (const float*)d_in[7];
  const float* gc2_w = (const float*)d_in[8];
  const float* gc2_b = (const float*)d_in[9];
  const float* fc_w = (const float*)d_in[10];
  const float* fc_b = (const float*)d_in[11];
  float* out = (float*)d_out;

  // workspace layout (all region sizes multiples of 16 B)
  char* ws = (char*)d_ws;
  _Float16* wfrag = (_Float16*)ws;                 // 12288
  _Float16* l1f = wfrag + 12288;                   // 4096
  _Float16* l2f = l1f + 4096;                      // 4096
  _Float16* fcf = l2f + 4096;                      // 1024  -> 43008 B total
  _Float16* hbuf = (_Float16*)(ws + 43008);        // NN*64 f16 = 6.4 MB
  _Float16* hw = hbuf + NN * 64;                   // NN*64 f16 = 6.4 MB
  float* dinv = (float*)(hw + NN * 64);            // NN f32 (200000 B)
  int* row_start = (int*)(dinv + NN);              // 50240 ints (200960 B)
  int* cellbase = row_start + 50240;               // NBG+4 ints (802832 B)
  int* part = cellbase + NBG + 4;                  // 512 ints
  unsigned int* rec = (unsigned int*)(part + 512); // EE u32 = 6.4 MB
  unsigned short* csr = (unsigned short*)(rec + EE); // EE u16 = 3.2 MB

  const int* esrc = edge_index;
  const int* edst = edge_index + EE;

  build_frags_kernel<<<84, 256, 0, stream>>>(w_hh, gc1_w, gc2_w, fc_w, wfrag);
  gru_kernel<<<NN / 16, 256, 0, stream>>>(x, w_ih, b_ih, b_hh, wfrag, hbuf);

  p1_hist_kernel<<<GP, 256, 0, stream>>>(edst, cellbase);
  scanA_kernel<<<SCB, 512, 0, stream>>>(cellbase, part);
  scanB_kernel<<<1, 512, 0, stream>>>(part);
  scanC_kernel<<<SCB, 512, 0, stream>>>(cellbase, part);
  p2_scatter_kernel<<<GP, 256, 0, stream>>>(esrc, edst, cellbase, rec);
  sort2_kernel<<<BK, 256, 0, stream>>>(rec, cellbase, csr, row_start, dinv);

  linear_mfma_kernel<<<(NN + 63) / 64, 256, 0, stream>>>(hbuf, l1f, dinv, hw);
  agg_kernel<<<(NN + 3) / 4, 256, 0, stream>>>(hw, dinv, row_start, csr, gc1_b, hbuf);
  linear_mfma_kernel<<<(NN + 63) / 64, 256, 0, stream>>>(hbuf, l2f, dinv, hw);
  agg_kernel<<<(NN + 3) / 4, 256, 0, stream>>>(hw, dinv, row_start, csr, gc2_b, hbuf);
  fc_mfma_kernel<<<(NN + 63) / 64, 256, 0, stream>>>(hbuf, fcf, fc_b, out);
}